// Round 1
// baseline (1378.544 us; speedup 1.0000x reference)
//
#include <hip/hip_runtime.h>

// ---------- types ----------
typedef __bf16 bf16x8 __attribute__((ext_vector_type(8)));
typedef float f32x4 __attribute__((ext_vector_type(4)));

__device__ __forceinline__ unsigned short f32_to_bf16u(float f) {
  unsigned int u = __float_as_uint(f);
  u += 0x7fffu + ((u >> 16) & 1u);   // RNE; no NaN inputs here
  return (unsigned short)(u >> 16);
}

// async global->LDS, 16B per lane. LDS dest must be wave-uniform base + lane*16.
__device__ __forceinline__ void async_copy16(const void* gptr, void* lptr) {
  __builtin_amdgcn_global_load_lds(
      (__attribute__((address_space(1))) void*)(unsigned long long)gptr,
      (__attribute__((address_space(3))) void*)(unsigned long long)lptr,
      16, 0, 0);
}

// ---------- dequant all 18 weights (int4 groups -> bf16 [out,in]), LoRA merged ----------
// wq4: [18,256,2048] int32, each packs lo/hi nibble -> flat positions 2j,2j+1.
// flat p within a weight = row-major [out=p>>10][in=p&1023]; group g = p>>12.
__global__ __launch_bounds__(256) void dequant_kernel(
    const int* __restrict__ wq4, const float* __restrict__ wnorm,
    const float* __restrict__ lora_a, const float* __restrict__ lora_b,
    unsigned short* __restrict__ Wd)
{
  const int gi = blockIdx.x * 256 + threadIdx.x;   // < 18*524288
  const int w = gi >> 19;
  const int rem = gi & 524287;
  const int q = wq4[gi];
  const float norm = wnorm[(w << 8) + (rem >> 11)];
  float w0 = (float)(q & 15) * (2.0f / 15.0f) - 1.0f;
  float w1 = (float)(q >> 4) * (2.0f / 15.0f) - 1.0f;
  w0 *= norm;
  w1 *= norm;
  const int p = rem << 1;
  // lin index 0,6,12 carry LoRA 0,1,2: W_eff = W + B@A
  const int li = (w == 0) ? 0 : (w == 6) ? 1 : (w == 12) ? 2 : -1;
  if (li >= 0) {
    const int o = p >> 10;
    const int col = p & 1023;              // even, so col+1 stays in-row
    const float* Ar = lora_a + li * 32768 + col;   // A[r][col], stride 1024
    const float* Br = lora_b + li * 32768 + o * 32; // B[o][r]
    float s0 = 0.f, s1 = 0.f;
#pragma unroll
    for (int r = 0; r < 32; r++) {
      const float br = Br[r];
      s0 += br * Ar[r * 1024];
      s1 += br * Ar[r * 1024 + 1];
    }
    w0 += s0;
    w1 += s1;
  }
  const unsigned int packed =
      ((unsigned int)f32_to_bf16u(w1) << 16) | (unsigned int)f32_to_bf16u(w0);
  *(unsigned int*)&Wd[((size_t)w << 20) + p] = packed;
}

// ---------- fp32 -> bf16 cast (x into h_bf) ----------
__global__ __launch_bounds__(256) void cast_bf16_kernel(
    const float* __restrict__ x, unsigned short* __restrict__ o)
{
  const int i = blockIdx.x * 256 + threadIdx.x;
  const float4 v = ((const float4*)x)[i];
  ushort4 b;
  b.x = f32_to_bf16u(v.x);
  b.y = f32_to_bf16u(v.y);
  b.z = f32_to_bf16u(v.z);
  b.w = f32_to_bf16u(v.w);
  ((ushort4*)o)[i] = b;
}

// ---------- bf16 MFMA GEMM: C[m,n] = sum_k A[m,k]*W[n,k] ----------
// 128x128 tile, BK=32, 256 threads = 4 waves in 2x2, each wave 4x4 of 16x16x32 MFMA.
// EPIL 0: relu -> bf16 out.  EPIL 1: + Res(fp32) -> fp32 out (no relu).
template <int EPIL>
__global__ __launch_bounds__(256) void gemm_bt(
    const unsigned short* __restrict__ A, const unsigned short* __restrict__ W,
    void* __restrict__ Out, const float* __restrict__ Res)
{
  constexpr int K = 1024;
  constexpr int N = 1024;
  __shared__ unsigned short As[128 * 32];  // 8 KB
  __shared__ unsigned short Ws[128 * 32];  // 8 KB

  const int tid = threadIdx.x;
  const int lane = tid & 63;
  const int wave = tid >> 6;
  const int m0 = blockIdx.y * 128;
  const int n0 = blockIdx.x * 128;
  const int wm = (wave >> 1) * 64;
  const int wn = (wave & 1) * 64;

  f32x4 acc[4][4];
#pragma unroll
  for (int i = 0; i < 4; i++)
#pragma unroll
    for (int j = 0; j < 4; j++) acc[i][j] = (f32x4){0.f, 0.f, 0.f, 0.f};

  // staging: chunk c = tid covers tile row c>>2, k-col8 (c&3)*8 (16B); 2 issues per tile
  const unsigned short* Ag = A + (size_t)(m0 + (tid >> 2)) * K + (tid & 3) * 8;
  const unsigned short* Wg = W + (size_t)(n0 + (tid >> 2)) * K + (tid & 3) * 8;
  unsigned short* As0 = &As[tid * 8];
  unsigned short* As1 = &As[2048 + tid * 8];
  unsigned short* Ws0 = &Ws[tid * 8];
  unsigned short* Ws1 = &Ws[2048 + tid * 8];

  const int fr = lane & 15;        // m (or n) within a 16-tile
  const int kk = (lane >> 4) * 8;  // k-offset of this lane's 8 elements

  for (int k0 = 0; k0 < K; k0 += 32) {
    async_copy16(Ag + k0, As0);
    async_copy16(Ag + 64 * K + k0, As1);
    async_copy16(Wg + k0, Ws0);
    async_copy16(Wg + 64 * K + k0, Ws1);
    __syncthreads();  // compiler emits vmcnt(0) drain before barrier
    bf16x8 a[4], b[4];
#pragma unroll
    for (int i = 0; i < 4; i++)
      a[i] = *(const bf16x8*)&As[(wm + i * 16 + fr) * 32 + kk];
#pragma unroll
    for (int j = 0; j < 4; j++)
      b[j] = *(const bf16x8*)&Ws[(wn + j * 16 + fr) * 32 + kk];
#pragma unroll
    for (int i = 0; i < 4; i++)
#pragma unroll
      for (int j = 0; j < 4; j++)
        acc[i][j] = __builtin_amdgcn_mfma_f32_16x16x32_bf16(a[i], b[j], acc[i][j], 0, 0, 0);
    __syncthreads();
  }

  // C/D layout: n = lane&15, m = (lane>>4)*4 + reg (verified m89/m91)
  const int rq = (lane >> 4) * 4;
#pragma unroll
  for (int i = 0; i < 4; i++) {
#pragma unroll
    for (int r = 0; r < 4; r++) {
      const int m = m0 + wm + i * 16 + rq + r;
#pragma unroll
      for (int j = 0; j < 4; j++) {
        const int n = n0 + wn + j * 16 + fr;
        float v = acc[i][j][r];
        if (EPIL == 0) {
          v = v > 0.f ? v : 0.f;
          ((unsigned short*)Out)[(size_t)m * N + n] = f32_to_bf16u(v);
        } else {
          ((float*)Out)[(size_t)m * N + n] = v + Res[(size_t)m * N + n];
        }
      }
    }
  }
}

// ---------- LayerNorm (fp32 in, writes bf16 + fp32) ----------
__global__ __launch_bounds__(256) void ln_kernel(
    const float* __restrict__ y, const float* __restrict__ gamma,
    const float* __restrict__ beta, unsigned short* __restrict__ h_bf,
    float* __restrict__ h_f32)
{
  const int row = blockIdx.x;
  const int tid = threadIdx.x;
  const size_t base = (size_t)row * 1024;
  const float4 v = ((const float4*)(y + base))[tid];
  float s = v.x + v.y + v.z + v.w;
  float s2 = v.x * v.x + v.y * v.y + v.z * v.z + v.w * v.w;
#pragma unroll
  for (int off = 32; off > 0; off >>= 1) {
    s += __shfl_down(s, off, 64);
    s2 += __shfl_down(s2, off, 64);
  }
  __shared__ float red[8];
  if ((tid & 63) == 0) {
    red[tid >> 6] = s;
    red[4 + (tid >> 6)] = s2;
  }
  __syncthreads();
  s = red[0] + red[1] + red[2] + red[3];
  s2 = red[4] + red[5] + red[6] + red[7];
  const float mu = s * (1.0f / 1024.0f);
  const float var = s2 * (1.0f / 1024.0f) - mu * mu;
  const float rs = rsqrtf(var + 1e-5f);
  const float4 g = ((const float4*)gamma)[tid];
  const float4 bb = ((const float4*)beta)[tid];
  float4 o;
  o.x = (v.x - mu) * rs * g.x + bb.x;
  o.y = (v.y - mu) * rs * g.y + bb.y;
  o.z = (v.z - mu) * rs * g.z + bb.z;
  o.w = (v.w - mu) * rs * g.w + bb.w;
  ((float4*)(h_f32 + base))[tid] = o;
  ushort4 ob;
  ob.x = f32_to_bf16u(o.x);
  ob.y = f32_to_bf16u(o.y);
  ob.z = f32_to_bf16u(o.z);
  ob.w = f32_to_bf16u(o.w);
  ((ushort4*)(h_bf + base))[tid] = ob;
}

// ---------- launch ----------
extern "C" void kernel_launch(void* const* d_in, const int* in_sizes, int n_in,
                              void* d_out, int out_size, void* d_ws, size_t ws_size,
                              hipStream_t stream)
{
  const float* x = (const float*)d_in[0];
  const int* wq4 = (const int*)d_in[1];
  const float* wnorm = (const float*)d_in[2];
  const float* lora_a = (const float*)d_in[3];
  const float* lora_b = (const float*)d_in[4];
  const float* ln_g = (const float*)d_in[5];
  const float* ln_b = (const float*)d_in[6];
  float* out = (float*)d_out;

  // ws layout (total ~196 MiB):
  char* ws = (char*)d_ws;
  unsigned short* Wd   = (unsigned short*)(ws);              // 18 * 1M bf16 = 36 MiB
  unsigned short* h_bf = (unsigned short*)(ws + 37748736);   // 32 MiB
  unsigned short* t1   = (unsigned short*)(ws + 71303168);   // 32 MiB
  unsigned short* t2   = (unsigned short*)(ws + 104857600);  // 32 MiB
  float* h_f32         = (float*)(ws + 138412032);           // 64 MiB

  dequant_kernel<<<36864, 256, 0, stream>>>(wq4, wnorm, lora_a, lora_b, Wd);
  cast_bf16_kernel<<<16384, 256, 0, stream>>>(x, h_bf);

  const unsigned short* hb = h_bf;
  const float* hres = x;  // block-0 residual straight from input (full fp32)
  for (int b = 0; b < 6; b++) {
    const unsigned short* W0 = Wd + (size_t)(3 * b + 0) * 1048576;
    const unsigned short* W1 = Wd + (size_t)(3 * b + 1) * 1048576;
    const unsigned short* W2 = Wd + (size_t)(3 * b + 2) * 1048576;
    gemm_bt<0><<<dim3(8, 128), 256, 0, stream>>>(hb, W0, t1, nullptr);
    gemm_bt<0><<<dim3(8, 128), 256, 0, stream>>>(t1, W1, t2, nullptr);
    // stage C: +residual, fp32, into d_out (scratch y for b<5, final for b==5)
    gemm_bt<1><<<dim3(8, 128), 256, 0, stream>>>(t2, W2, out, hres);
    if (b < 5) {
      ln_kernel<<<16384, 256, 0, stream>>>(out, ln_g + b * 1024, ln_b + b * 1024,
                                           h_bf, h_f32);
      hb = h_bf;
      hres = h_f32;
    }
  }
  (void)in_sizes; (void)n_in; (void)out_size; (void)ws_size;
}

// Round 2
// 1040.559 us; speedup vs baseline: 1.3248x; 1.3248x over previous
//
#include <hip/hip_runtime.h>

// ---------- types ----------
typedef __bf16 bf16x8 __attribute__((ext_vector_type(8)));
typedef float f32x4 __attribute__((ext_vector_type(4)));

__device__ __forceinline__ unsigned short f32_to_bf16u(float f) {
  unsigned int u = __float_as_uint(f);
  u += 0x7fffu + ((u >> 16) & 1u);   // RNE; no NaN inputs here
  return (unsigned short)(u >> 16);
}

// async global->LDS, 16B per lane. LDS dest is wave-uniform base + lane*16.
__device__ __forceinline__ void async_copy16(const void* gptr, void* lptr) {
  __builtin_amdgcn_global_load_lds(
      (__attribute__((address_space(1))) void*)(unsigned long long)gptr,
      (__attribute__((address_space(3))) void*)(unsigned long long)lptr,
      16, 0, 0);
}

// ---------- dequant all 18 weights (int4 groups -> bf16 [out,in]), LoRA merged ----------
__global__ __launch_bounds__(256) void dequant_kernel(
    const int* __restrict__ wq4, const float* __restrict__ wnorm,
    const float* __restrict__ lora_a, const float* __restrict__ lora_b,
    unsigned short* __restrict__ Wd)
{
  const int gi = blockIdx.x * 256 + threadIdx.x;   // < 18*524288
  const int w = gi >> 19;
  const int rem = gi & 524287;
  const int q = wq4[gi];
  const float norm = wnorm[(w << 8) + (rem >> 11)];
  float w0 = (float)(q & 15) * (2.0f / 15.0f) - 1.0f;
  float w1 = (float)(q >> 4) * (2.0f / 15.0f) - 1.0f;
  w0 *= norm;
  w1 *= norm;
  const int p = rem << 1;
  const int li = (w == 0) ? 0 : (w == 6) ? 1 : (w == 12) ? 2 : -1;
  if (li >= 0) {
    const int o = p >> 10;
    const int col = p & 1023;
    const float* Ar = lora_a + li * 32768 + col;    // A[r][col], stride 1024
    const float* Br = lora_b + li * 32768 + o * 32; // B[o][r]
    float s0 = 0.f, s1 = 0.f;
#pragma unroll
    for (int r = 0; r < 32; r++) {
      const float br = Br[r];
      s0 += br * Ar[r * 1024];
      s1 += br * Ar[r * 1024 + 1];
    }
    w0 += s0;
    w1 += s1;
  }
  const unsigned int packed =
      ((unsigned int)f32_to_bf16u(w1) << 16) | (unsigned int)f32_to_bf16u(w0);
  *(unsigned int*)&Wd[((size_t)w << 20) + p] = packed;
}

// ---------- fp32 -> bf16 cast ----------
__global__ __launch_bounds__(256) void cast_bf16_kernel(
    const float* __restrict__ x, unsigned short* __restrict__ o)
{
  const int i = blockIdx.x * 256 + threadIdx.x;
  const float4 v = ((const float4*)x)[i];
  ushort4 b;
  b.x = f32_to_bf16u(v.x);
  b.y = f32_to_bf16u(v.y);
  b.z = f32_to_bf16u(v.z);
  b.w = f32_to_bf16u(v.w);
  ((ushort4*)o)[i] = b;
}

// ---------- bf16 MFMA GEMM: C[m,n] = sum_k A[m,k]*W[n,k] ----------
// 128x128 tile, BK=64, 256 threads = 4 waves (2x2), each wave 4x4 of 16x16x32.
// XCD-aware linear-grid swizzle: bid&7 = XCD slab (16 m-tiles), n fastest
// inside so the A-tile is L2-reused 8x and the whole 2MB W stays L2-resident.
// LDS uses an XOR-of-row bank swizzle applied on the GLOBAL source index
// (global_load_lds lane->LDS mapping is identity; we permute what each lane
// fetches instead): phys col8 = logical col8 ^ (row&7).
// EPIL 0: relu -> bf16 out.  EPIL 1: + Res(fp32) -> fp32 out (no relu).
template <int EPIL>
__global__ __launch_bounds__(256, 4) void gemm_bt(
    const unsigned short* __restrict__ A, const unsigned short* __restrict__ W,
    void* __restrict__ Out, const float* __restrict__ Res)
{
  constexpr int K = 1024;
  constexpr int N = 1024;
  __shared__ unsigned short As[128 * 64];  // 16 KB
  __shared__ unsigned short Ws[128 * 64];  // 16 KB

  const int tid = threadIdx.x;
  const int lane = tid & 63;
  const int wave = tid >> 6;

  const int bid = blockIdx.x;           // 0..1023
  const int xcd = bid & 7;
  const int j = bid >> 3;               // 0..127 per-XCD sequence
  const int m0 = (xcd * 16 + (j >> 3)) * 128;
  const int n0 = (j & 7) * 128;

  const int wm = (wave >> 1) * 64;
  const int wn = (wave & 1) * 64;

  f32x4 acc[4][4];
#pragma unroll
  for (int i = 0; i < 4; i++)
#pragma unroll
    for (int jj = 0; jj < 4; jj++) acc[i][jj] = (f32x4){0.f, 0.f, 0.f, 0.f};

  // staging: issue i covers rows i*32..i*32+31; thread -> row tid>>3, col8 slot tid&7.
  // XOR swizzle on source: logical col8 = (tid&7) ^ ((tid>>3)&7).
  const int arow = tid >> 3;
  const int acol8 = (tid & 7) ^ (arow & 7);
  const unsigned short* Ag = A + (size_t)(m0 + arow) * K + acol8 * 8;
  const unsigned short* Wg = W + (size_t)(n0 + arow) * K + acol8 * 8;
  unsigned short* Asd = &As[tid * 8];   // = row*64 + (tid&7)*8, contiguous per lane
  unsigned short* Wsd = &Ws[tid * 8];

  const int fr = lane & 15;    // m (or n) within a 16-tile
  const int q = lane >> 4;     // quad index -> k-chunk

  for (int k0 = 0; k0 < K; k0 += 64) {
#pragma unroll
    for (int i = 0; i < 4; i++)
      async_copy16(Ag + (size_t)i * 32 * K + k0, Asd + i * 2048);
#pragma unroll
    for (int i = 0; i < 4; i++)
      async_copy16(Wg + (size_t)i * 32 * K + k0, Wsd + i * 2048);
    __syncthreads();
#pragma unroll
    for (int h = 0; h < 2; h++) {
      const int kk8 = q + h * 4;           // logical 8-col group
      bf16x8 a[4], b[4];
#pragma unroll
      for (int i = 0; i < 4; i++) {
        const int row = wm + i * 16 + fr;
        a[i] = *(const bf16x8*)&As[row * 64 + ((kk8 ^ (fr & 7)) << 3)];
      }
#pragma unroll
      for (int jj = 0; jj < 4; jj++) {
        const int row = wn + jj * 16 + fr;
        b[jj] = *(const bf16x8*)&Ws[row * 64 + ((kk8 ^ (fr & 7)) << 3)];
      }
#pragma unroll
      for (int i = 0; i < 4; i++)
#pragma unroll
        for (int jj = 0; jj < 4; jj++)
          acc[i][jj] = __builtin_amdgcn_mfma_f32_16x16x32_bf16(a[i], b[jj], acc[i][jj], 0, 0, 0);
    }
    __syncthreads();
  }

  // C/D layout: n = lane&15, m = (lane>>4)*4 + reg  (verified m89/m91)
  const int rq = q * 4;
#pragma unroll
  for (int i = 0; i < 4; i++) {
#pragma unroll
    for (int r = 0; r < 4; r++) {
      const int m = m0 + wm + i * 16 + rq + r;
#pragma unroll
      for (int jj = 0; jj < 4; jj++) {
        const int n = n0 + wn + jj * 16 + fr;
        float v = acc[i][jj][r];
        if (EPIL == 0) {
          v = v > 0.f ? v : 0.f;
          ((unsigned short*)Out)[(size_t)m * N + n] = f32_to_bf16u(v);
        } else {
          ((float*)Out)[(size_t)m * N + n] = v + Res[(size_t)m * N + n];
        }
      }
    }
  }
}

// ---------- LayerNorm (fp32 in, writes bf16 + fp32) ----------
__global__ __launch_bounds__(256) void ln_kernel(
    const float* __restrict__ y, const float* __restrict__ gamma,
    const float* __restrict__ beta, unsigned short* __restrict__ h_bf,
    float* __restrict__ h_f32)
{
  const int row = blockIdx.x;
  const int tid = threadIdx.x;
  const size_t base = (size_t)row * 1024;
  const float4 v = ((const float4*)(y + base))[tid];
  float s = v.x + v.y + v.z + v.w;
  float s2 = v.x * v.x + v.y * v.y + v.z * v.z + v.w * v.w;
#pragma unroll
  for (int off = 32; off > 0; off >>= 1) {
    s += __shfl_down(s, off, 64);
    s2 += __shfl_down(s2, off, 64);
  }
  __shared__ float red[8];
  if ((tid & 63) == 0) {
    red[tid >> 6] = s;
    red[4 + (tid >> 6)] = s2;
  }
  __syncthreads();
  s = red[0] + red[1] + red[2] + red[3];
  s2 = red[4] + red[5] + red[6] + red[7];
  const float mu = s * (1.0f / 1024.0f);
  const float var = s2 * (1.0f / 1024.0f) - mu * mu;
  const float rs = rsqrtf(var + 1e-5f);
  const float4 g = ((const float4*)gamma)[tid];
  const float4 bb = ((const float4*)beta)[tid];
  float4 o;
  o.x = (v.x - mu) * rs * g.x + bb.x;
  o.y = (v.y - mu) * rs * g.y + bb.y;
  o.z = (v.z - mu) * rs * g.z + bb.z;
  o.w = (v.w - mu) * rs * g.w + bb.w;
  ((float4*)(h_f32 + base))[tid] = o;
  ushort4 ob;
  ob.x = f32_to_bf16u(o.x);
  ob.y = f32_to_bf16u(o.y);
  ob.z = f32_to_bf16u(o.z);
  ob.w = f32_to_bf16u(o.w);
  ((ushort4*)(h_bf + base))[tid] = ob;
}

// ---------- launch ----------
extern "C" void kernel_launch(void* const* d_in, const int* in_sizes, int n_in,
                              void* d_out, int out_size, void* d_ws, size_t ws_size,
                              hipStream_t stream)
{
  const float* x = (const float*)d_in[0];
  const int* wq4 = (const int*)d_in[1];
  const float* wnorm = (const float*)d_in[2];
  const float* lora_a = (const float*)d_in[3];
  const float* lora_b = (const float*)d_in[4];
  const float* ln_g = (const float*)d_in[5];
  const float* ln_b = (const float*)d_in[6];
  float* out = (float*)d_out;

  char* ws = (char*)d_ws;
  unsigned short* Wd   = (unsigned short*)(ws);              // 36 MiB
  unsigned short* h_bf = (unsigned short*)(ws + 37748736);   // 32 MiB
  unsigned short* t1   = (unsigned short*)(ws + 71303168);   // 32 MiB
  unsigned short* t2   = (unsigned short*)(ws + 104857600);  // 32 MiB
  float* h_f32         = (float*)(ws + 138412032);           // 64 MiB

  dequant_kernel<<<36864, 256, 0, stream>>>(wq4, wnorm, lora_a, lora_b, Wd);
  cast_bf16_kernel<<<16384, 256, 0, stream>>>(x, h_bf);

  const unsigned short* hb = h_bf;
  const float* hres = x;
  for (int b = 0; b < 6; b++) {
    const unsigned short* W0 = Wd + (size_t)(3 * b + 0) * 1048576;
    const unsigned short* W1 = Wd + (size_t)(3 * b + 1) * 1048576;
    const unsigned short* W2 = Wd + (size_t)(3 * b + 2) * 1048576;
    gemm_bt<0><<<1024, 256, 0, stream>>>(hb, W0, t1, nullptr);
    gemm_bt<0><<<1024, 256, 0, stream>>>(t1, W1, t2, nullptr);
    gemm_bt<1><<<1024, 256, 0, stream>>>(t2, W2, out, hres);
    if (b < 5) {
      ln_kernel<<<16384, 256, 0, stream>>>(out, ln_g + b * 1024, ln_b + b * 1024,
                                           h_bf, h_f32);
      hb = h_bf;
      hres = h_f32;
    }
  }
  (void)in_sizes; (void)n_in; (void)out_size; (void)ws_size;
}